// Round 1
// 317.270 us; speedup vs baseline: 1.0009x; 1.0009x over previous
//
#include <hip/hip_runtime.h>
#include <math.h>

#define IMG_H 1080
#define IMG_W 1920
#define HW (IMG_H * IMG_W)
#define NBATCH 8

typedef float f4 __attribute__((ext_vector_type(4)));

// ---------------- compile-time DCT/quant tables ----------------
// 0.5*cos(j*pi/16), f64 values rounded to f32 by the literal, j=0..8
constexpr float HCONST[9] = {
    0.5f,
    0.49039264020161522f,
    0.46193976625564337f,
    0.41573480615127262f,
    0.35355339059327376f,
    0.27778511650980109f,
    0.19134171618254489f,
    0.097545161008064135f,
    0.0f};

// basis[k][n] = sqrt(2/8)*cos(pi*k*(2n+1)/16); basis[0][n] = sqrt(1/8).
// Bit-identical to the reference's f64-computed, f32-rounded table.
constexpr float fbasis(int k, int n) {
    if (k == 0) return 0.35355339059327373f;  // sqrt(1/8)
    int m = (k * (2 * n + 1)) & 31;           // cos(pi*m/16), period 32
    float s = 1.0f;
    if (m > 16) m = 32 - m;                   // cos(2pi - x) = cos(x)
    if (m > 8) { m = 16 - m; s = -1.0f; }     // cos(pi - x) = -cos(x)
    return s * HCONST[m];
}

constexpr int BASEQC[64] = {
    16, 11, 10, 16, 24, 40, 51, 61,
    12, 12, 14, 19, 26, 58, 60, 55,
    14, 13, 16, 24, 40, 57, 69, 56,
    14, 17, 22, 29, 51, 87, 80, 62,
    18, 22, 37, 56, 68, 109, 103, 77,
    24, 35, 55, 64, 81, 104, 113, 92,
    49, 64, 78, 87, 103, 121, 120, 101,
    72, 92, 95, 98, 112, 100, 103, 99};

struct alignas(16) T64 { float v[64]; };

constexpr T64 gen_bl() {  // row-major basis: v[k*8+n] = basis[k][n]
    T64 t{};
    for (int k = 0; k < 8; ++k)
        for (int n = 0; n < 8; ++n) t.v[k * 8 + n] = fbasis(k, n);
    return t;
}
constexpr T64 gen_bt() {  // transposed basis: v[l*8+j] = basis[j][l]
    T64 t{};
    for (int l = 0; l < 8; ++l)
        for (int j = 0; j < 8; ++j) t.v[l * 8 + j] = fbasis(j, l);
    return t;
}
constexpr T64 gen_qt() {  // transposed quant: v[l*8+k] = base[k][l]*144/50 (all > 1)
    T64 t{};
    for (int l = 0; l < 8; ++l)
        for (int k = 0; k < 8; ++k)
            t.v[l * 8 + k] = (float)(BASEQC[k * 8 + l] * 144) / 50.0f;
    return t;
}

constexpr T64 BLc = gen_bl();                 // compile-time-folded (SGPR literals)
__device__ __constant__ T64 d_BL = gen_bl();  // per-lane basis row l
__device__ __constant__ T64 d_BT = gen_bt();  // per-lane basis column l
__device__ __constant__ T64 d_QT = gen_qt();  // per-lane quant column l

__device__ __forceinline__ float clamp255(float v) {
    return fminf(fmaxf(v, 0.0f), 255.0f);
}

// Wave-internal LDS hand-off: order compiler, wait LDS writes retired
// (lgkmcnt(0) only — vmcnt left unconstrained so in-flight global loads stay out).
__device__ __forceinline__ void wave_lds_fence() {
    __builtin_amdgcn_wave_barrier();
    __builtin_amdgcn_s_waitcnt(0xC07F);  // vmcnt(63) expcnt(7) lgkmcnt(0)
    __builtin_amdgcn_wave_barrier();
}

// j-ascending fma chain starting from 0 (matches original scalar loop numerics)
__device__ __forceinline__ float dot8(f4 d0, f4 d1, f4 w0, f4 w1) {
    float acc = 0.0f;
    acc = fmaf(d0.x, w0.x, acc);
    acc = fmaf(d0.y, w0.y, acc);
    acc = fmaf(d0.z, w0.z, acc);
    acc = fmaf(d0.w, w0.w, acc);
    acc = fmaf(d1.x, w1.x, acc);
    acc = fmaf(d1.y, w1.y, acc);
    acc = fmaf(d1.z, w1.z, acc);
    acc = fmaf(d1.w, w1.w, acc);
    return acc;
}

// 192 threads = 3 independent waves; each wave owns an 8-row x 64-col strip
// (8 DCT blocks). No s_barrier anywhere: all LDS traffic is wave-private.
__global__ __launch_bounds__(192) void h264_kernel(const float* __restrict__ x,
                                                   float* __restrict__ out) {
    __shared__ __align__(16) float yt[3 * 512];   // per-wave luma/yd tile (8x64)
    // per-wave double transpose buf: 2 bufs x 8 blk x (8 rows x stride 12 + 4 pad)
    __shared__ __align__(16) float t2[3 * 1600];

    const int t = threadIdx.x;
    const int wave = t >> 6;
    const int lane = t & 63;
    const int blk = lane >> 3;
    const int l = lane & 7;

    const int h0 = blockIdx.y * 8;
    const int wcol0 = blockIdx.x * 192 + wave * 64;
    const int bat = blockIdx.z;
    const float* xb = x + (size_t)bat * 3 * HW;
    float* ob = out + (size_t)bat * 3 * HW;

    float* ytw = yt + wave * 512;
    float* t2w = t2 + wave * 1600;
    // blk stride 100 floats: b128 row reads start at bank (4*blk + 12*k) % 32
    // -> 8 disjoint 4-bank spans across the 8 blocks: conflict-free.
    float* t2A = t2w + blk * 100;
    float* t2B = t2w + 800 + blk * 100;

    // ---- phase 1: nontemporal f4 loads, luma -> wave-private LDS;
    //      keep b/g/r in registers for the epilogue
    f4 Bv[2], Gv[2], Rv[2];
    int gaddr[2];
#pragma unroll
    for (int it = 0; it < 2; ++it) {
        int idx = lane + (it << 6);   // 0..127 f4 slots of this wave's strip
        int row = idx >> 4;           // 8 rows x 16 f4/row
        int c4 = (idx & 15) << 2;     // float offset within strip
        int ga = (h0 + row) * IMG_W + wcol0 + c4;
        gaddr[it] = ga;
        Bv[it] = __builtin_nontemporal_load((const f4*)(xb + ga));
        Gv[it] = __builtin_nontemporal_load((const f4*)(xb + HW + ga));
        Rv[it] = __builtin_nontemporal_load((const f4*)(xb + 2 * HW + ga));
        f4 y4;
        // y = (0.114*b + 0.587*g) + 0.299*r, no fma contraction (match ref)
        y4.x = __fadd_rn(__fadd_rn(__fmul_rn(0.114f, Bv[it].x), __fmul_rn(0.587f, Gv[it].x)), __fmul_rn(0.299f, Rv[it].x));
        y4.y = __fadd_rn(__fadd_rn(__fmul_rn(0.114f, Bv[it].y), __fmul_rn(0.587f, Gv[it].y)), __fmul_rn(0.299f, Rv[it].y));
        y4.z = __fadd_rn(__fadd_rn(__fmul_rn(0.114f, Bv[it].z), __fmul_rn(0.587f, Gv[it].z)), __fmul_rn(0.299f, Rv[it].z));
        y4.w = __fadd_rn(__fadd_rn(__fmul_rn(0.114f, Bv[it].w), __fmul_rn(0.587f, Gv[it].w)), __fmul_rn(0.299f, Rv[it].w));
        *(f4*)(ytw + row * 64 + c4) = y4;
    }

    // per-lane table rows: 96 B/lane from L2-resident __constant__ tables;
    // issued here, consumed in phases 3/4 (latency hidden under phase 2)
    const f4 blr0 = *(const f4*)(d_BL.v + l * 8);        // basis[l][0..3]
    const f4 blr1 = *((const f4*)(d_BL.v + l * 8) + 1);  // basis[l][4..7]
    const f4 blc0 = *(const f4*)(d_BT.v + l * 8);        // basis[0..3][l]
    const f4 blc1 = *((const f4*)(d_BT.v + l * 8) + 1);  // basis[4..7][l]
    const f4 qc0 = *(const f4*)(d_QT.v + l * 8);         // quant[0..3][l]
    const f4 qc1 = *((const f4*)(d_QT.v + l * 8) + 1);   // quant[4..7][l]
    const float qv[8] = {qc0.x, qc0.y, qc0.z, qc0.w, qc1.x, qc1.y, qc1.z, qc1.w};

    wave_lds_fence();

    // ---- phase 2: column DCT; basis entries are compile-time constants
    float ycol[8];
#pragma unroll
    for (int i = 0; i < 8; ++i) ycol[i] = ytw[i * 64 + lane];
#pragma unroll
    for (int k = 0; k < 8; ++k) {
        float acc = 0.0f;
#pragma unroll
        for (int i = 0; i < 8; ++i) acc = fmaf(BLc.v[k * 8 + i], ycol[i], acc);
        t2A[k * 12 + l] = acc;  // C1 row-major, stride 12 (16B-aligned rows)
    }
    wave_lds_fence();

    // ---- phase 3: row DCT + quantize -> t2B (double buffer: no WAR fence)
#pragma unroll
    for (int k = 0; k < 8; ++k) {
        const f4 r0 = *(const f4*)(t2A + k * 12);        // C1[k][0..3]
        const f4 r1 = *((const f4*)(t2A + k * 12) + 1);  // C1[k][4..7]
        float acc = dot8(r0, r1, blr0, blr1);
        const float q = qv[k];
        // round-half-even division, matches jnp.round(coef/(q+1e-8)) (+1e-8 vanishes in f32)
        t2B[k * 12 + l] = __fmul_rn(rintf(__fdiv_rn(acc, q)), q);
    }
    wave_lds_fence();

    // ---- phase 4: inverse DCT
    float sv[8];
#pragma unroll
    for (int i = 0; i < 8; ++i) {
        const f4 r0 = *(const f4*)(t2B + i * 12);        // Cq[i][0..3]
        const f4 r1 = *((const f4*)(t2B + i * 12) + 1);  // Cq[i][4..7]
        sv[i] = dot8(r0, r1, blc0, blc1);
    }
#pragma unroll
    for (int k = 0; k < 8; ++k) {
        float acc = 0.0f;
#pragma unroll
        for (int i = 0; i < 8; ++i) acc = fmaf(BLc.v[i * 8 + k], sv[i], acc);
        ytw[k * 64 + lane] = __fsub_rn(acc, ycol[k]);  // yd
    }
    wave_lds_fence();

    // ---- phase 5: vectorized epilogue reusing registered b/g/r; nt stores
#pragma unroll
    for (int it = 0; it < 2; ++it) {
        int idx = lane + (it << 6);
        int row = idx >> 4;
        int c4 = (idx & 15) << 2;
        f4 y4 = *(f4*)(ytw + row * 64 + c4);
        int ga = gaddr[it];
        f4 o0, o1, o2;
        o0.x = clamp255(__fadd_rn(Bv[it].x, __fmul_rn(0.114f, y4.x)));
        o0.y = clamp255(__fadd_rn(Bv[it].y, __fmul_rn(0.114f, y4.y)));
        o0.z = clamp255(__fadd_rn(Bv[it].z, __fmul_rn(0.114f, y4.z)));
        o0.w = clamp255(__fadd_rn(Bv[it].w, __fmul_rn(0.114f, y4.w)));
        o1.x = clamp255(__fadd_rn(Gv[it].x, __fmul_rn(0.587f, y4.x)));
        o1.y = clamp255(__fadd_rn(Gv[it].y, __fmul_rn(0.587f, y4.y)));
        o1.z = clamp255(__fadd_rn(Gv[it].z, __fmul_rn(0.587f, y4.z)));
        o1.w = clamp255(__fadd_rn(Gv[it].w, __fmul_rn(0.587f, y4.w)));
        o2.x = clamp255(__fadd_rn(Rv[it].x, __fmul_rn(0.299f, y4.x)));
        o2.y = clamp255(__fadd_rn(Rv[it].y, __fmul_rn(0.299f, y4.y)));
        o2.z = clamp255(__fadd_rn(Rv[it].z, __fmul_rn(0.299f, y4.z)));
        o2.w = clamp255(__fadd_rn(Rv[it].w, __fmul_rn(0.299f, y4.w)));
        __builtin_nontemporal_store(o0, (f4*)(ob + ga));
        __builtin_nontemporal_store(o1, (f4*)(ob + HW + ga));
        __builtin_nontemporal_store(o2, (f4*)(ob + 2 * HW + ga));
    }
}

extern "C" void kernel_launch(void* const* d_in, const int* in_sizes, int n_in,
                              void* d_out, int out_size, void* d_ws, size_t ws_size,
                              hipStream_t stream) {
    const float* x = (const float*)d_in[0];
    float* out = (float*)d_out;
    dim3 grid(IMG_W / 192, IMG_H / 8, NBATCH);  // 10 x 135 x 8
    dim3 block(192);
    h264_kernel<<<grid, block, 0, stream>>>(x, out);
}